// Round 9
// baseline (84.351 us; speedup 1.0000x reference)
//
#include <hip/hip_runtime.h>
#include <hip/hip_bf16.h>
#include <cstdint>
#include <cstddef>

typedef __attribute__((ext_vector_type(8))) short bf16x8;
typedef __attribute__((ext_vector_type(4))) float f32x4;

__device__ __forceinline__ unsigned short f2bf(float f) {
  union { float f; unsigned u; } v; v.f = f;
  unsigned r = v.u + 0x7FFFu + ((v.u >> 16) & 1u);
  return (unsigned short)(r >> 16);
}

__device__ __forceinline__ float bf2f(unsigned short h) {
  union { float f; unsigned u; } c; c.u = ((unsigned)h) << 16;
  return c.f;
}

__device__ __forceinline__ void gload_lds16(const void* g, void* l) {
  __builtin_amdgcn_global_load_lds(
      (const __attribute__((address_space(1))) unsigned int*)g,
      (__attribute__((address_space(3))) unsigned int*)l, 16, 0, 0);
}

__device__ __forceinline__ void st_agent(float* p, float v) {
  __hip_atomic_store(p, v, __ATOMIC_RELAXED, __HIP_MEMORY_SCOPE_AGENT);
}
__device__ __forceinline__ float ld_agent(const float* p) {
  return __hip_atomic_load(p, __ATOMIC_RELAXED, __HIP_MEMORY_SCOPE_AGENT);
}

// ---------------------------------------------------------------------------
// K01 fused: identical to R8 (proven).
// ---------------------------------------------------------------------------
__global__ __launch_bounds__(256) void k01_prep(const float* __restrict__ W,
                                                unsigned short* __restrict__ Wt,
                                                const float* __restrict__ x,
                                                unsigned short* __restrict__ xbf,
                                                float* __restrict__ rnorm,
                                                float* __restrict__ s,
                                                int* __restrict__ cnt2) {
  __shared__ __align__(16) char sm[16640];
  __shared__ int lf;
  int tid = threadIdx.x;
  if (blockIdx.x < 256) {
    float (*tile)[65] = (float(*)[65])sm;
    int k0 = (blockIdx.x & 15) * 64;
    int c0 = (blockIdx.x >> 4) * 64;
    int tx = tid & 63;
    int ty = tid >> 6;
#pragma unroll
    for (int i = 0; i < 16; ++i) {
      int r = i * 4 + ty;
      int c = c0 + tx;
      tile[r][tx] = (c < 1000) ? W[(size_t)(k0 + r) * 1000 + c] : 0.f;
    }
    __syncthreads();
#pragma unroll
    for (int i = 0; i < 16; ++i) {
      int ct = i * 4 + ty;
      int cg = c0 + ct;
      if (cg != 1000)
        Wt[(size_t)cg * 1024 + (k0 + tx)] = f2bf(tile[tx][ct]);
    }
    return;
  }
  float (*sblk)[1024] = (float(*)[1024])sm;
  int bid = blockIdx.x - 256;
  int wid = tid >> 6, lane = tid & 63;
  float4 sacc[4];
#pragma unroll
  for (int j = 0; j < 4; ++j) sacc[j] = make_float4(0.f, 0.f, 0.f, 0.f);
#pragma unroll
  for (int r = 0; r < 4; ++r) {
    int row = bid * 16 + wid * 4 + r;
    const float4* xr = (const float4*)(x + (size_t)row * 1024);
    float4 v[4];
    float ss = 0.f;
#pragma unroll
    for (int j = 0; j < 4; ++j) {
      v[j] = xr[lane + j * 64];
      ss += v[j].x * v[j].x + v[j].y * v[j].y + v[j].z * v[j].z + v[j].w * v[j].w;
    }
#pragma unroll
    for (int m = 1; m < 64; m <<= 1) ss += __shfl_xor(ss, m);
    float rn = 1.f / fmaxf(sqrtf(ss), 1e-8f);
    if (lane == 0) rnorm[row] = rn;
#pragma unroll
    for (int j = 0; j < 4; ++j) {
      ushort4 hv;
      hv.x = f2bf(v[j].x); hv.y = f2bf(v[j].y);
      hv.z = f2bf(v[j].z); hv.w = f2bf(v[j].w);
      ((ushort4*)(xbf + (size_t)row * 1024))[lane + j * 64] = hv;
      sacc[j].x += v[j].x * rn; sacc[j].y += v[j].y * rn;
      sacc[j].z += v[j].z * rn; sacc[j].w += v[j].w * rn;
    }
  }
#pragma unroll
  for (int j = 0; j < 4; ++j) ((float4*)sblk[wid])[j * 64 + lane] = sacc[j];
  __syncthreads();
  for (int d = tid; d < 1024; d += 256) {
    float t = sblk[0][d] + sblk[1][d] + sblk[2][d] + sblk[3][d];
    atomicAdd(&s[d], t);
  }
  asm volatile("s_waitcnt vmcnt(0)" ::: "memory");
  __syncthreads();
  if (tid == 0) lf = (atomicAdd(cnt2, 1) == 511) ? 1 : 0;
  __syncthreads();
  if (lf) {
    ushort4 h;
    h.x = f2bf(ld_agent(&s[tid * 4 + 0]));
    h.y = f2bf(ld_agent(&s[tid * 4 + 1]));
    h.z = f2bf(ld_agent(&s[tid * 4 + 2]));
    h.w = f2bf(ld_agent(&s[tid * 4 + 3]));
    ((ushort4*)(Wt + (size_t)1000 * 1024))[tid] = h;
  }
}

// ---------------------------------------------------------------------------
// K3: identical to R8 (proven). Launched TWICE this round as a duration
// probe: replay-start memset zeroes cnt; run 1 drives cnt[rb] 0->8 and fires
// the fixup exactly once (atomicAdd old==7); run 2 sees old 8..15, fixup
// never re-fires, out untouched; pm/pz/ps/pd rewritten with bitwise-identical
// values. Delta vs R8 total = k3 warm-operand duration.
// ---------------------------------------------------------------------------
#define LDSBUF 49152

__global__ __launch_bounds__(512) void k3_gemm(const unsigned short* __restrict__ xbf,
                                               const unsigned short* __restrict__ wt,
                                               const float* __restrict__ bias,
                                               const float* __restrict__ rnorm,
                                               float* __restrict__ pm,
                                               float* __restrict__ pz,
                                               float* __restrict__ ps,
                                               float* __restrict__ pd,
                                               int* __restrict__ cnt,
                                               float* __restrict__ out) {
  __shared__ __align__(16) char lds[147456];
  __shared__ int lastflag;

  int tid = threadIdx.x;
  int lane = tid & 63;
  int wid = tid >> 6;
  int wc = wid & 1;
  int wr = wid >> 1;
  int cb = blockIdx.x >> 5;   // cls chunk (0..7): same-rb blocks share an XCD
  int rb = blockIdx.x & 31;   // row block (0..31) -> XCD = rb % 8
  int C0 = cb * 128;
  int R0 = rb * 256;

  float bv[4][4];
#pragma unroll
  for (int mf = 0; mf < 4; ++mf)
#pragma unroll
    for (int q = 0; q < 4; ++q) {
      int cls_g = C0 + wc * 64 + mf * 16 + (lane >> 4) * 4 + q;
      bv[mf][q] = (cls_g < 1000) ? bias[cls_g] : ((cls_g == 1000) ? 0.f : -1e30f);
    }
  f32x4 acc[4][4];
#pragma unroll
  for (int mf = 0; mf < 4; ++mf)
#pragma unroll
    for (int nf = 0; nf < 4; ++nf)
#pragma unroll
      for (int q = 0; q < 4; ++q) acc[mf][nf][q] = bv[mf][q];

  const char* gA = (const char*)(wt + (size_t)C0 * 1024);
  const char* gB = (const char*)(xbf + (size_t)R0 * 1024);
  int grow = lane >> 3;
  int gswz = ((lane & 7) ^ grow) << 4;

#define STA(kt, b, r)                                                          \
  gload_lds16(gA + (size_t)((r) * 64 + wid * 8 + grow) * 2048 + (kt) * 128 +   \
                  gswz,                                                        \
              lds + (b) * LDSBUF + (r) * 8192 + wid * 1024)
#define STB(kt, b, r)                                                          \
  gload_lds16(gB + (size_t)((r) * 64 + wid * 8 + grow) * 2048 + (kt) * 128 +   \
                  gswz,                                                        \
              lds + (b) * LDSBUF + 16384 + (r) * 8192 + wid * 1024)

  STA(0, 0, 0); STA(0, 0, 1); STB(0, 0, 0); STB(0, 0, 1); STB(0, 0, 2); STB(0, 0, 3);
  STA(1, 1, 0); STA(1, 1, 1); STB(1, 1, 0); STB(1, 1, 1); STB(1, 1, 2); STB(1, 1, 3);

  int rsw = (lane & 7) << 4;
  int kcol = (lane >> 4) * 16;

  auto ktile = [&](const char* A, const char* B, int nt, int nb, bool pf) {
    if (pf) { STA(nt, nb, 0); STA(nt, nb, 1); }
    bf16x8 a[4][2];
#pragma unroll
    for (int mf = 0; mf < 4; ++mf)
#pragma unroll
      for (int ks = 0; ks < 2; ++ks)
        a[mf][ks] = *(const bf16x8*)(A + (wc * 64 + mf * 16 + (lane & 15)) * 128 +
                                     ((ks * 64 + kcol) ^ rsw));
    {
      bf16x8 b0[2];
#pragma unroll
      for (int ks = 0; ks < 2; ++ks)
        b0[ks] = *(const bf16x8*)(B + (wr * 64 + 0 * 16 + (lane & 15)) * 128 +
                                  ((ks * 64 + kcol) ^ rsw));
      __builtin_amdgcn_s_setprio(1);
#pragma unroll
      for (int ks = 0; ks < 2; ++ks)
#pragma unroll
        for (int mf = 0; mf < 4; ++mf)
          acc[mf][0] = __builtin_amdgcn_mfma_f32_16x16x32_bf16(a[mf][ks], b0[ks],
                                                               acc[mf][0], 0, 0, 0);
      __builtin_amdgcn_s_setprio(0);
    }
    if (pf) { STB(nt, nb, 0); STB(nt, nb, 1); }
    {
      bf16x8 b1[2];
#pragma unroll
      for (int ks = 0; ks < 2; ++ks)
        b1[ks] = *(const bf16x8*)(B + (wr * 64 + 1 * 16 + (lane & 15)) * 128 +
                                  ((ks * 64 + kcol) ^ rsw));
      __builtin_amdgcn_s_setprio(1);
#pragma unroll
      for (int ks = 0; ks < 2; ++ks)
#pragma unroll
        for (int mf = 0; mf < 4; ++mf)
          acc[mf][1] = __builtin_amdgcn_mfma_f32_16x16x32_bf16(a[mf][ks], b1[ks],
                                                               acc[mf][1], 0, 0, 0);
      __builtin_amdgcn_s_setprio(0);
    }
    if (pf) { STB(nt, nb, 2); STB(nt, nb, 3); }
    {
      bf16x8 b2[2];
#pragma unroll
      for (int ks = 0; ks < 2; ++ks)
        b2[ks] = *(const bf16x8*)(B + (wr * 64 + 2 * 16 + (lane & 15)) * 128 +
                                  ((ks * 64 + kcol) ^ rsw));
      __builtin_amdgcn_s_setprio(1);
#pragma unroll
      for (int ks = 0; ks < 2; ++ks)
#pragma unroll
        for (int mf = 0; mf < 4; ++mf)
          acc[mf][2] = __builtin_amdgcn_mfma_f32_16x16x32_bf16(a[mf][ks], b2[ks],
                                                               acc[mf][2], 0, 0, 0);
      __builtin_amdgcn_s_setprio(0);
    }
    {
      bf16x8 b3[2];
#pragma unroll
      for (int ks = 0; ks < 2; ++ks)
        b3[ks] = *(const bf16x8*)(B + (wr * 64 + 3 * 16 + (lane & 15)) * 128 +
                                  ((ks * 64 + kcol) ^ rsw));
      __builtin_amdgcn_s_setprio(1);
#pragma unroll
      for (int ks = 0; ks < 2; ++ks)
#pragma unroll
        for (int mf = 0; mf < 4; ++mf)
          acc[mf][3] = __builtin_amdgcn_mfma_f32_16x16x32_bf16(a[mf][ks], b3[ks],
                                                               acc[mf][3], 0, 0, 0);
      __builtin_amdgcn_s_setprio(0);
    }
  };

  for (int t = 0; t < 15; ++t) {
    asm volatile("s_waitcnt vmcnt(6)" ::: "memory");
    __builtin_amdgcn_s_barrier();
    asm volatile("" ::: "memory");
    const char* A = lds + (t % 3) * LDSBUF;
    ktile(A, A + 16384, t + 2, (t + 2) % 3, t < 14);
  }
  asm volatile("s_waitcnt vmcnt(0)" ::: "memory");
  __builtin_amdgcn_s_barrier();
  asm volatile("" ::: "memory");
  {
    const char* A = lds + (15 % 3) * LDSBUF;
    ktile(A, A + 16384, 0, 0, false);
  }

  if (cb == 7 && wc == 1 && ((lane >> 4) == 2)) {
#pragma unroll
    for (int nf = 0; nf < 4; ++nf) {
      int r = wr * 64 + nf * 16 + (lane & 15);
      st_agent(&pd[(size_t)rb * 256 + r], acc[2][nf][0]);
      acc[2][nf][0] = -1e30f;
    }
  }

  __syncthreads();
  float* mm = (float*)lds;
  float* zz = mm + 512;
  float* sv = zz + 512;
#pragma unroll
  for (int nf = 0; nf < 4; ++nf) {
    float m1 = -1e30f;
#pragma unroll
    for (int mf = 0; mf < 4; ++mf)
#pragma unroll
      for (int q = 0; q < 4; ++q) m1 = fmaxf(m1, acc[mf][nf][q]);
    m1 = fmaxf(m1, __shfl_xor(m1, 16));
    m1 = fmaxf(m1, __shfl_xor(m1, 32));
    float z1 = 0.f, s1 = 0.f;
#pragma unroll
    for (int mf = 0; mf < 4; ++mf)
#pragma unroll
      for (int q = 0; q < 4; ++q) {
        float tt = acc[mf][nf][q] - m1;
        float e = expf(tt);
        z1 += e;
        s1 += e * tt;
      }
    z1 += __shfl_xor(z1, 16); z1 += __shfl_xor(z1, 32);
    s1 += __shfl_xor(s1, 16); s1 += __shfl_xor(s1, 32);
    if (lane < 16) {
      int r = wr * 64 + nf * 16 + lane;
      mm[wc * 256 + r] = m1;
      zz[wc * 256 + r] = z1;
      sv[wc * 256 + r] = s1;
    }
  }
  __syncthreads();
  if (tid < 256) {
    float m0 = mm[tid], mA = mm[256 + tid];
    float z0 = zz[tid], zA = zz[256 + tid];
    float s0 = sv[tid], sA = sv[256 + tid];
    float M = fmaxf(m0, mA);
    float e0 = expf(m0 - M), e1 = expf(mA - M);
    float Z = z0 * e0 + zA * e1;
    float S = e0 * (s0 + (m0 - M) * z0) + e1 * (sA + (mA - M) * zA);
    size_t o = (size_t)cb * 8192 + R0 + tid;
    st_agent(&pm[o], M);
    st_agent(&pz[o], Z);
    st_agent(&ps[o], S);
  }

  asm volatile("s_waitcnt vmcnt(0)" ::: "memory");
  __syncthreads();
  if (tid == 0) lastflag = (atomicAdd(&cnt[rb], 1) == 7) ? 1 : 0;
  __syncthreads();
  if (lastflag && tid < 256) {
    int row = R0 + tid;
    float mv[8], zv[8], svv[8];
    float M = -1e30f;
#pragma unroll
    for (int c = 0; c < 8; ++c) {
      mv[c] = ld_agent(&pm[(size_t)c * 8192 + row]);
      zv[c] = ld_agent(&pz[(size_t)c * 8192 + row]);
      svv[c] = ld_agent(&ps[(size_t)c * 8192 + row]);
      M = fmaxf(M, mv[c]);
    }
    float Z = 0.f, S = 0.f;
#pragma unroll
    for (int c = 0; c < 8; ++c) {
      float e = expf(mv[c] - M);
      Z += zv[c] * e;
      S += e * (svv[c] + (mv[c] - M) * zv[c]);
    }
    float loss = S / Z - logf(Z);
    float dotv = ld_agent(&pd[(size_t)rb * 256 + tid]);
    out[row] = loss * dotv * rnorm[row] * (1.f / 8192.f);
  }
}

// ---------------------------------------------------------------------------
extern "C" void kernel_launch(void* const* d_in, const int* in_sizes, int n_in,
                              void* d_out, int out_size, void* d_ws, size_t ws_size,
                              hipStream_t stream) {
  (void)in_sizes; (void)n_in; (void)out_size; (void)ws_size;
  const float* x = (const float*)d_in[0];
  const float* W = (const float*)d_in[1];
  const float* b = (const float*)d_in[2];
  float* out = (float*)d_out;
  char* ws = (char*)d_ws;

  unsigned short* Wt = (unsigned short*)(ws + 0);           // 2 MiB
  unsigned short* xbf = (unsigned short*)(ws + 2097152);    // 16 MiB
  float* rnorm = (float*)(ws + 18874368);                   // 32 KiB
  float* s = (float*)(ws + 18907136);                       // 4 KiB
  int* cnt2 = (int*)(ws + 18911232);                        // 4 B
  int* cnt = (int*)(ws + 18911236);                         // 128 B
  float* pm = (float*)(ws + 18915328);                      // 256 KiB
  float* pz = (float*)(ws + 18915328 + 262144);
  float* ps = (float*)(ws + 18915328 + 524288);
  float* pd = (float*)(ws + 18915328 + 786432);             // 32 KiB

  hipMemsetAsync(s, 0, 8192, stream);  // covers s + cnt2 + cnt
  k01_prep<<<768, 256, 0, stream>>>(W, Wt, x, xbf, rnorm, s, cnt2);
  // k3 launched twice: run 1 computes everything incl. fixup (cnt 0->8);
  // run 2 is a pure duration probe (cnt 8->16, fixup never re-fires, out
  // untouched, pm/pz/ps/pd rewritten with identical values). Deterministic.
  k3_gemm<<<256, 512, 0, stream>>>(xbf, Wt, b, rnorm, pm, pz, ps, pd, cnt, out);
  k3_gemm<<<256, 512, 0, stream>>>(xbf, Wt, b, rnorm, pm, pz, ps, pd, cnt, out);
}

// Round 11
// 67.781 us; speedup vs baseline: 1.2445x; 1.2445x over previous
//
#include <hip/hip_runtime.h>
#include <hip/hip_bf16.h>
#include <cstdint>
#include <cstddef>

typedef __attribute__((ext_vector_type(8))) short bf16x8;
typedef __attribute__((ext_vector_type(4))) float f32x4;

__device__ __forceinline__ unsigned short f2bf(float f) {
  union { float f; unsigned u; } v; v.f = f;
  unsigned r = v.u + 0x7FFFu + ((v.u >> 16) & 1u);
  return (unsigned short)(r >> 16);
}

__device__ __forceinline__ float bf2f(unsigned short h) {
  union { float f; unsigned u; } c; c.u = ((unsigned)h) << 16;
  return c.f;
}

__device__ __forceinline__ void gload_lds16(const void* g, void* l) {
  __builtin_amdgcn_global_load_lds(
      (const __attribute__((address_space(1))) unsigned int*)g,
      (__attribute__((address_space(3))) unsigned int*)l, 16, 0, 0);
}

__device__ __forceinline__ void st_agent(float* p, float v) {
  __hip_atomic_store(p, v, __ATOMIC_RELAXED, __HIP_MEMORY_SCOPE_AGENT);
}
__device__ __forceinline__ float ld_agent(const float* p) {
  return __hip_atomic_load(p, __ATOMIC_RELAXED, __HIP_MEMORY_SCOPE_AGENT);
}

// ---------------------------------------------------------------------------
// K01 v2 (R10 + LDS-size fix): UNIFORM grid 256 x 512 thr (1 block/CU, all
// co-resident). Each block: (a) one 64x64 W-transpose tile -> Wt bf16
// (pad 0); (b) 32 x-rows: rnorm, x->bf16, s += xn. R10 BUG: sm was 49920 but
// sblk @17408 + 32768 = 50176 -> wave-7 tail overflowed -> garbage in
// s[960..1023]. Fixed: sm[50176].
// ---------------------------------------------------------------------------
__global__ __launch_bounds__(512) void k01_prep(const float* __restrict__ W,
                                                unsigned short* __restrict__ Wt,
                                                const float* __restrict__ x,
                                                unsigned short* __restrict__ xbf,
                                                float* __restrict__ rnorm,
                                                float* __restrict__ s) {
  __shared__ __align__(16) char sm[50176];  // tile 16640B | sblk 32KB @17408
  int tid = threadIdx.x;
  int b = blockIdx.x;

  // (a) W transpose tile: k [k0,k0+64), cls [c0,c0+64)
  {
    float (*tile)[65] = (float(*)[65])sm;
    int k0 = (b & 15) * 64;
    int c0 = (b >> 4) * 64;
    int tx = tid & 63;
    int ty = tid >> 6;  // 0..7
#pragma unroll
    for (int i = 0; i < 8; ++i) {
      int r = i * 8 + ty;
      int c = c0 + tx;
      tile[r][tx] = (c < 1000) ? W[(size_t)(k0 + r) * 1000 + c] : 0.f;
    }
    __syncthreads();
#pragma unroll
    for (int i = 0; i < 8; ++i) {
      int ct = i * 8 + ty;
      Wt[(size_t)(c0 + ct) * 1024 + (k0 + tx)] = f2bf(tile[tx][ct]);
    }
  }

  // (b) norm/convert rows [32b, 32b+32)
  {
    float (*sblk)[1024] = (float(*)[1024])(sm + 17408);
    int wid = tid >> 6, lane = tid & 63;
    float4 sacc[4];
#pragma unroll
    for (int j = 0; j < 4; ++j) sacc[j] = make_float4(0.f, 0.f, 0.f, 0.f);
#pragma unroll
    for (int r = 0; r < 4; ++r) {
      int row = b * 32 + wid * 4 + r;
      const float4* xr = (const float4*)(x + (size_t)row * 1024);
      float4 v[4];
      float ss = 0.f;
#pragma unroll
      for (int j = 0; j < 4; ++j) {
        v[j] = xr[lane + j * 64];
        ss += v[j].x * v[j].x + v[j].y * v[j].y + v[j].z * v[j].z + v[j].w * v[j].w;
      }
#pragma unroll
      for (int m = 1; m < 64; m <<= 1) ss += __shfl_xor(ss, m);
      float rn = 1.f / fmaxf(sqrtf(ss), 1e-8f);
      if (lane == 0) rnorm[row] = rn;
#pragma unroll
      for (int j = 0; j < 4; ++j) {
        ushort4 hv;
        hv.x = f2bf(v[j].x); hv.y = f2bf(v[j].y);
        hv.z = f2bf(v[j].z); hv.w = f2bf(v[j].w);
        ((ushort4*)(xbf + (size_t)row * 1024))[lane + j * 64] = hv;
        sacc[j].x += v[j].x * rn; sacc[j].y += v[j].y * rn;
        sacc[j].z += v[j].z * rn; sacc[j].w += v[j].w * rn;
      }
    }
#pragma unroll
    for (int j = 0; j < 4; ++j) ((float4*)sblk[wid])[j * 64 + lane] = sacc[j];
    __syncthreads();
#pragma unroll
    for (int d = tid; d < 1024; d += 512) {
      float t = 0.f;
#pragma unroll
      for (int w = 0; w < 8; ++w) t += sblk[w][d];
      atomicAdd(&s[d], t);  // device-scope RMW at coherence point
    }
  }
}

// ---------------------------------------------------------------------------
// K3: R8's proven GEMM (tri-buffer, depth-2 prefetch, vmcnt(6), XOR-swizzle,
// XCD-aligned factorization cb=b>>5, rb=b&31) + softmax partials + fence-free
// split-K fixup. No class-1000 (cls >= 1000 masked -1e30); fixup computes
// dot(x_row, s) directly (s 4KB + xbf panel, both L2-hot).
// ---------------------------------------------------------------------------
#define LDSBUF 49152

__global__ __launch_bounds__(512) void k3_gemm(const unsigned short* __restrict__ xbf,
                                               const unsigned short* __restrict__ wt,
                                               const float* __restrict__ bias,
                                               const float* __restrict__ rnorm,
                                               const float* __restrict__ s,
                                               float* __restrict__ pm,
                                               float* __restrict__ pz,
                                               float* __restrict__ ps,
                                               int* __restrict__ cnt,
                                               float* __restrict__ out) {
  __shared__ __align__(16) char lds[147456];
  __shared__ int lastflag;

  int tid = threadIdx.x;
  int lane = tid & 63;
  int wid = tid >> 6;
  int wc = wid & 1;
  int wr = wid >> 1;
  int cb = blockIdx.x >> 5;   // cls chunk: same-rb blocks share an XCD
  int rb = blockIdx.x & 31;   // row block -> XCD = rb % 8
  int C0 = cb * 128;
  int R0 = rb * 256;

  float bv[4][4];
#pragma unroll
  for (int mf = 0; mf < 4; ++mf)
#pragma unroll
    for (int q = 0; q < 4; ++q) {
      int cls_g = C0 + wc * 64 + mf * 16 + (lane >> 4) * 4 + q;
      bv[mf][q] = (cls_g < 1000) ? bias[cls_g] : -1e30f;
    }
  f32x4 acc[4][4];
#pragma unroll
  for (int mf = 0; mf < 4; ++mf)
#pragma unroll
    for (int nf = 0; nf < 4; ++nf)
#pragma unroll
      for (int q = 0; q < 4; ++q) acc[mf][nf][q] = bv[mf][q];

  const char* gA = (const char*)(wt + (size_t)C0 * 1024);
  const char* gB = (const char*)(xbf + (size_t)R0 * 1024);
  int grow = lane >> 3;
  int gswz = ((lane & 7) ^ grow) << 4;

#define STA(kt, b, r)                                                          \
  gload_lds16(gA + (size_t)((r) * 64 + wid * 8 + grow) * 2048 + (kt) * 128 +   \
                  gswz,                                                        \
              lds + (b) * LDSBUF + (r) * 8192 + wid * 1024)
#define STB(kt, b, r)                                                          \
  gload_lds16(gB + (size_t)((r) * 64 + wid * 8 + grow) * 2048 + (kt) * 128 +   \
                  gswz,                                                        \
              lds + (b) * LDSBUF + 16384 + (r) * 8192 + wid * 1024)

  STA(0, 0, 0); STA(0, 0, 1); STB(0, 0, 0); STB(0, 0, 1); STB(0, 0, 2); STB(0, 0, 3);
  STA(1, 1, 0); STA(1, 1, 1); STB(1, 1, 0); STB(1, 1, 1); STB(1, 1, 2); STB(1, 1, 3);

  int rsw = (lane & 7) << 4;
  int kcol = (lane >> 4) * 16;

  auto ktile = [&](const char* A, const char* B, int nt, int nb, bool pf) {
    if (pf) { STA(nt, nb, 0); STA(nt, nb, 1); }
    bf16x8 a[4][2];
#pragma unroll
    for (int mf = 0; mf < 4; ++mf)
#pragma unroll
      for (int ks = 0; ks < 2; ++ks)
        a[mf][ks] = *(const bf16x8*)(A + (wc * 64 + mf * 16 + (lane & 15)) * 128 +
                                     ((ks * 64 + kcol) ^ rsw));
    {
      bf16x8 b0[2];
#pragma unroll
      for (int ks = 0; ks < 2; ++ks)
        b0[ks] = *(const bf16x8*)(B + (wr * 64 + 0 * 16 + (lane & 15)) * 128 +
                                  ((ks * 64 + kcol) ^ rsw));
      __builtin_amdgcn_s_setprio(1);
#pragma unroll
      for (int ks = 0; ks < 2; ++ks)
#pragma unroll
        for (int mf = 0; mf < 4; ++mf)
          acc[mf][0] = __builtin_amdgcn_mfma_f32_16x16x32_bf16(a[mf][ks], b0[ks],
                                                               acc[mf][0], 0, 0, 0);
      __builtin_amdgcn_s_setprio(0);
    }
    if (pf) { STB(nt, nb, 0); STB(nt, nb, 1); }
    {
      bf16x8 b1[2];
#pragma unroll
      for (int ks = 0; ks < 2; ++ks)
        b1[ks] = *(const bf16x8*)(B + (wr * 64 + 1 * 16 + (lane & 15)) * 128 +
                                  ((ks * 64 + kcol) ^ rsw));
      __builtin_amdgcn_s_setprio(1);
#pragma unroll
      for (int ks = 0; ks < 2; ++ks)
#pragma unroll
        for (int mf = 0; mf < 4; ++mf)
          acc[mf][1] = __builtin_amdgcn_mfma_f32_16x16x32_bf16(a[mf][ks], b1[ks],
                                                               acc[mf][1], 0, 0, 0);
      __builtin_amdgcn_s_setprio(0);
    }
    if (pf) { STB(nt, nb, 2); STB(nt, nb, 3); }
    {
      bf16x8 b2[2];
#pragma unroll
      for (int ks = 0; ks < 2; ++ks)
        b2[ks] = *(const bf16x8*)(B + (wr * 64 + 2 * 16 + (lane & 15)) * 128 +
                                  ((ks * 64 + kcol) ^ rsw));
      __builtin_amdgcn_s_setprio(1);
#pragma unroll
      for (int ks = 0; ks < 2; ++ks)
#pragma unroll
        for (int mf = 0; mf < 4; ++mf)
          acc[mf][2] = __builtin_amdgcn_mfma_f32_16x16x32_bf16(a[mf][ks], b2[ks],
                                                               acc[mf][2], 0, 0, 0);
      __builtin_amdgcn_s_setprio(0);
    }
    {
      bf16x8 b3[2];
#pragma unroll
      for (int ks = 0; ks < 2; ++ks)
        b3[ks] = *(const bf16x8*)(B + (wr * 64 + 3 * 16 + (lane & 15)) * 128 +
                                  ((ks * 64 + kcol) ^ rsw));
      __builtin_amdgcn_s_setprio(1);
#pragma unroll
      for (int ks = 0; ks < 2; ++ks)
#pragma unroll
        for (int mf = 0; mf < 4; ++mf)
          acc[mf][3] = __builtin_amdgcn_mfma_f32_16x16x32_bf16(a[mf][ks], b3[ks],
                                                               acc[mf][3], 0, 0, 0);
      __builtin_amdgcn_s_setprio(0);
    }
  };

  for (int t = 0; t < 15; ++t) {
    asm volatile("s_waitcnt vmcnt(6)" ::: "memory");
    __builtin_amdgcn_s_barrier();
    asm volatile("" ::: "memory");
    const char* A = lds + (t % 3) * LDSBUF;
    ktile(A, A + 16384, t + 2, (t + 2) % 3, t < 14);
  }
  asm volatile("s_waitcnt vmcnt(0)" ::: "memory");
  __builtin_amdgcn_s_barrier();
  asm volatile("" ::: "memory");
  {
    const char* A = lds + (15 % 3) * LDSBUF;
    ktile(A, A + 16384, 0, 0, false);
  }

  __syncthreads();
  float* mm = (float*)lds;
  float* zz = mm + 512;
  float* sv = zz + 512;
#pragma unroll
  for (int nf = 0; nf < 4; ++nf) {
    float m1 = -1e30f;
#pragma unroll
    for (int mf = 0; mf < 4; ++mf)
#pragma unroll
      for (int q = 0; q < 4; ++q) m1 = fmaxf(m1, acc[mf][nf][q]);
    m1 = fmaxf(m1, __shfl_xor(m1, 16));
    m1 = fmaxf(m1, __shfl_xor(m1, 32));
    float z1 = 0.f, s1 = 0.f;
#pragma unroll
    for (int mf = 0; mf < 4; ++mf)
#pragma unroll
      for (int q = 0; q < 4; ++q) {
        float tt = acc[mf][nf][q] - m1;
        float e = expf(tt);
        z1 += e;
        s1 += e * tt;
      }
    z1 += __shfl_xor(z1, 16); z1 += __shfl_xor(z1, 32);
    s1 += __shfl_xor(s1, 16); s1 += __shfl_xor(s1, 32);
    if (lane < 16) {
      int r = wr * 64 + nf * 16 + lane;
      mm[wc * 256 + r] = m1;
      zz[wc * 256 + r] = z1;
      sv[wc * 256 + r] = s1;
    }
  }
  __syncthreads();
  if (tid < 256) {
    float m0 = mm[tid], mA = mm[256 + tid];
    float z0 = zz[tid], zA = zz[256 + tid];
    float s0 = sv[tid], sA = sv[256 + tid];
    float M = fmaxf(m0, mA);
    float e0 = expf(m0 - M), e1 = expf(mA - M);
    float Z = z0 * e0 + zA * e1;
    float S = e0 * (s0 + (m0 - M) * z0) + e1 * (sA + (mA - M) * zA);
    size_t o = (size_t)cb * 8192 + R0 + tid;
    st_agent(&pm[o], M);
    st_agent(&pz[o], Z);
    st_agent(&ps[o], S);
  }

  // Fence-free split-K fixup: 8th-arriving block per rb merges -> out.
  asm volatile("s_waitcnt vmcnt(0)" ::: "memory");
  __syncthreads();
  if (tid == 0) lastflag = (atomicAdd(&cnt[rb], 1) == 7) ? 1 : 0;
  __syncthreads();
  if (lastflag) {
    // s -> LDS (4KB, L2-hot; kernel boundary made it coherent)
    float* sld = (float*)(lds + 4096);
    for (int d = tid; d < 1024; d += 512) sld[d] = s[d];
    __syncthreads();
    // dot(x_row, s): 2 threads/row over the L2-hot xbf panel
    float* dotl = (float*)(lds + 8192);
    int rr = tid >> 1, half = tid & 1;
    int row = R0 + rr;
    const bf16x8* xr = (const bf16x8*)(xbf + (size_t)row * 1024 + half * 512);
    const float4* sp = (const float4*)(sld + half * 512);
    float d = 0.f;
#pragma unroll 8
    for (int j = 0; j < 64; ++j) {
      bf16x8 v = xr[j];
      float4 sa = sp[j * 2], sb = sp[j * 2 + 1];
      d += bf2f((unsigned short)v[0]) * sa.x + bf2f((unsigned short)v[1]) * sa.y +
           bf2f((unsigned short)v[2]) * sa.z + bf2f((unsigned short)v[3]) * sa.w +
           bf2f((unsigned short)v[4]) * sb.x + bf2f((unsigned short)v[5]) * sb.y +
           bf2f((unsigned short)v[6]) * sb.z + bf2f((unsigned short)v[7]) * sb.w;
    }
    d += __shfl_xor(d, 1);
    if (half == 0) dotl[rr] = d;
    __syncthreads();
    if (tid < 256) {
      int orow = R0 + tid;
      float mv[8], zv[8], svv[8];
      float M = -1e30f;
#pragma unroll
      for (int c = 0; c < 8; ++c) {
        mv[c] = ld_agent(&pm[(size_t)c * 8192 + orow]);
        zv[c] = ld_agent(&pz[(size_t)c * 8192 + orow]);
        svv[c] = ld_agent(&ps[(size_t)c * 8192 + orow]);
        M = fmaxf(M, mv[c]);
      }
      float Z = 0.f, S = 0.f;
#pragma unroll
      for (int c = 0; c < 8; ++c) {
        float e = expf(mv[c] - M);
        Z += zv[c] * e;
        S += e * (svv[c] + (mv[c] - M) * zv[c]);
      }
      float loss = S / Z - logf(Z);
      out[orow] = loss * dotl[tid] * rnorm[orow] * (1.f / 8192.f);
    }
  }
}

// ---------------------------------------------------------------------------
extern "C" void kernel_launch(void* const* d_in, const int* in_sizes, int n_in,
                              void* d_out, int out_size, void* d_ws, size_t ws_size,
                              hipStream_t stream) {
  (void)in_sizes; (void)n_in; (void)out_size; (void)ws_size;
  const float* x = (const float*)d_in[0];
  const float* W = (const float*)d_in[1];
  const float* b = (const float*)d_in[2];
  float* out = (float*)d_out;
  char* ws = (char*)d_ws;

  unsigned short* Wt = (unsigned short*)(ws + 0);           // 2 MiB
  unsigned short* xbf = (unsigned short*)(ws + 2097152);    // 16 MiB
  float* rnorm = (float*)(ws + 18874368);                   // 32 KiB
  float* s = (float*)(ws + 18907136);                       // 4 KiB
  int* cnt = (int*)(ws + 18911232);                         // 32 ints
  float* pm = (float*)(ws + 18915328);                      // 256 KiB
  float* pz = (float*)(ws + 18915328 + 262144);
  float* ps = (float*)(ws + 18915328 + 524288);

  hipMemsetAsync(s, 0, 8192, stream);  // covers s + cnt
  k01_prep<<<256, 512, 0, stream>>>(W, Wt, x, xbf, rnorm, s);
  k3_gemm<<<256, 512, 0, stream>>>(xbf, Wt, b, rnorm, s, pm, pz, ps, cnt, out);
}

// Round 12
// 53.157 us; speedup vs baseline: 1.5869x; 1.2751x over previous
//
#include <hip/hip_runtime.h>
#include <hip/hip_bf16.h>
#include <cstdint>
#include <cstddef>

typedef __attribute__((ext_vector_type(8))) short bf16x8;
typedef __attribute__((ext_vector_type(4))) float f32x4;

__device__ __forceinline__ unsigned short f2bf(float f) {
  union { float f; unsigned u; } v; v.f = f;
  unsigned r = v.u + 0x7FFFu + ((v.u >> 16) & 1u);
  return (unsigned short)(r >> 16);
}

__device__ __forceinline__ float bf2f(unsigned short h) {
  union { float f; unsigned u; } c; c.u = ((unsigned)h) << 16;
  return c.f;
}

__device__ __forceinline__ void gload_lds16(const void* g, void* l) {
  __builtin_amdgcn_global_load_lds(
      (const __attribute__((address_space(1))) unsigned int*)g,
      (__attribute__((address_space(3))) unsigned int*)l, 16, 0, 0);
}

// ---------------------------------------------------------------------------
// K01: uniform grid 256 x 512 (R11-proven). Each block: one 64x64 W-transpose
// tile -> Wt bf16 (pad 0) + 32 x-rows (rnorm, x->bf16, s += xn atomics).
// ---------------------------------------------------------------------------
__global__ __launch_bounds__(512) void k01_prep(const float* __restrict__ W,
                                                unsigned short* __restrict__ Wt,
                                                const float* __restrict__ x,
                                                unsigned short* __restrict__ xbf,
                                                float* __restrict__ rnorm,
                                                float* __restrict__ s) {
  __shared__ __align__(16) char sm[50176];  // tile 16640B | sblk 32KB @17408
  int tid = threadIdx.x;
  int b = blockIdx.x;

  {
    float (*tile)[65] = (float(*)[65])sm;
    int k0 = (b & 15) * 64;
    int c0 = (b >> 4) * 64;
    int tx = tid & 63;
    int ty = tid >> 6;  // 0..7
#pragma unroll
    for (int i = 0; i < 8; ++i) {
      int r = i * 8 + ty;
      int c = c0 + tx;
      tile[r][tx] = (c < 1000) ? W[(size_t)(k0 + r) * 1000 + c] : 0.f;
    }
    __syncthreads();
#pragma unroll
    for (int i = 0; i < 8; ++i) {
      int ct = i * 8 + ty;
      Wt[(size_t)(c0 + ct) * 1024 + (k0 + tx)] = f2bf(tile[tx][ct]);
    }
  }

  {
    float (*sblk)[1024] = (float(*)[1024])(sm + 17408);
    int wid = tid >> 6, lane = tid & 63;
    float4 sacc[4];
#pragma unroll
    for (int j = 0; j < 4; ++j) sacc[j] = make_float4(0.f, 0.f, 0.f, 0.f);
#pragma unroll
    for (int r = 0; r < 4; ++r) {
      int row = b * 32 + wid * 4 + r;
      const float4* xr = (const float4*)(x + (size_t)row * 1024);
      float4 v[4];
      float ss = 0.f;
#pragma unroll
      for (int j = 0; j < 4; ++j) {
        v[j] = xr[lane + j * 64];
        ss += v[j].x * v[j].x + v[j].y * v[j].y + v[j].z * v[j].z + v[j].w * v[j].w;
      }
#pragma unroll
      for (int m = 1; m < 64; m <<= 1) ss += __shfl_xor(ss, m);
      float rn = 1.f / fmaxf(sqrtf(ss), 1e-8f);
      if (lane == 0) rnorm[row] = rn;
#pragma unroll
      for (int j = 0; j < 4; ++j) {
        ushort4 hv;
        hv.x = f2bf(v[j].x); hv.y = f2bf(v[j].y);
        hv.z = f2bf(v[j].z); hv.w = f2bf(v[j].w);
        ((ushort4*)(xbf + (size_t)row * 1024))[lane + j * 64] = hv;
        sacc[j].x += v[j].x * rn; sacc[j].y += v[j].y * rn;
        sacc[j].z += v[j].z * rn; sacc[j].w += v[j].w * rn;
      }
    }
#pragma unroll
    for (int j = 0; j < 4; ++j) ((float4*)sblk[wid])[j * 64 + lane] = sacc[j];
    __syncthreads();
#pragma unroll
    for (int d = tid; d < 1024; d += 512) {
      float t = 0.f;
#pragma unroll
      for (int w = 0; w < 8; ++w) t += sblk[w][d];
      atomicAdd(&s[d], t);
    }
  }
}

// ---------------------------------------------------------------------------
// K3: pure GEMM + softmax partials. R11's loop (tri-buffer, depth-2 prefetch,
// counted vmcnt(6), XOR-swizzle, XCD-aligned cb=b>>5/rb=b&31) with the
// split-K fixup REMOVED (R11 counters: in-kernel fixup = +19us serial tail).
// Partials written with plain stores (kernel boundary provides visibility).
// ---------------------------------------------------------------------------
#define LDSBUF 49152

__global__ __launch_bounds__(512) void k3_gemm(const unsigned short* __restrict__ xbf,
                                               const unsigned short* __restrict__ wt,
                                               const float* __restrict__ bias,
                                               float* __restrict__ pm,
                                               float* __restrict__ pz,
                                               float* __restrict__ ps) {
  __shared__ __align__(16) char lds[147456];

  int tid = threadIdx.x;
  int lane = tid & 63;
  int wid = tid >> 6;
  int wc = wid & 1;
  int wr = wid >> 1;
  int cb = blockIdx.x >> 5;   // cls chunk: same-rb blocks share an XCD
  int rb = blockIdx.x & 31;   // row block -> XCD = rb % 8
  int C0 = cb * 128;
  int R0 = rb * 256;

  float bv[4][4];
#pragma unroll
  for (int mf = 0; mf < 4; ++mf)
#pragma unroll
    for (int q = 0; q < 4; ++q) {
      int cls_g = C0 + wc * 64 + mf * 16 + (lane >> 4) * 4 + q;
      bv[mf][q] = (cls_g < 1000) ? bias[cls_g] : -1e30f;
    }
  f32x4 acc[4][4];
#pragma unroll
  for (int mf = 0; mf < 4; ++mf)
#pragma unroll
    for (int nf = 0; nf < 4; ++nf)
#pragma unroll
      for (int q = 0; q < 4; ++q) acc[mf][nf][q] = bv[mf][q];

  const char* gA = (const char*)(wt + (size_t)C0 * 1024);
  const char* gB = (const char*)(xbf + (size_t)R0 * 1024);
  int grow = lane >> 3;
  int gswz = ((lane & 7) ^ grow) << 4;

#define STA(kt, b, r)                                                          \
  gload_lds16(gA + (size_t)((r) * 64 + wid * 8 + grow) * 2048 + (kt) * 128 +   \
                  gswz,                                                        \
              lds + (b) * LDSBUF + (r) * 8192 + wid * 1024)
#define STB(kt, b, r)                                                          \
  gload_lds16(gB + (size_t)((r) * 64 + wid * 8 + grow) * 2048 + (kt) * 128 +   \
                  gswz,                                                        \
              lds + (b) * LDSBUF + 16384 + (r) * 8192 + wid * 1024)

  STA(0, 0, 0); STA(0, 0, 1); STB(0, 0, 0); STB(0, 0, 1); STB(0, 0, 2); STB(0, 0, 3);
  STA(1, 1, 0); STA(1, 1, 1); STB(1, 1, 0); STB(1, 1, 1); STB(1, 1, 2); STB(1, 1, 3);

  int rsw = (lane & 7) << 4;
  int kcol = (lane >> 4) * 16;

  auto ktile = [&](const char* A, const char* B, int nt, int nb, bool pf) {
    if (pf) { STA(nt, nb, 0); STA(nt, nb, 1); }
    bf16x8 a[4][2];
#pragma unroll
    for (int mf = 0; mf < 4; ++mf)
#pragma unroll
      for (int ks = 0; ks < 2; ++ks)
        a[mf][ks] = *(const bf16x8*)(A + (wc * 64 + mf * 16 + (lane & 15)) * 128 +
                                     ((ks * 64 + kcol) ^ rsw));
    {
      bf16x8 b0[2];
#pragma unroll
      for (int ks = 0; ks < 2; ++ks)
        b0[ks] = *(const bf16x8*)(B + (wr * 64 + 0 * 16 + (lane & 15)) * 128 +
                                  ((ks * 64 + kcol) ^ rsw));
      __builtin_amdgcn_s_setprio(1);
#pragma unroll
      for (int ks = 0; ks < 2; ++ks)
#pragma unroll
        for (int mf = 0; mf < 4; ++mf)
          acc[mf][0] = __builtin_amdgcn_mfma_f32_16x16x32_bf16(a[mf][ks], b0[ks],
                                                               acc[mf][0], 0, 0, 0);
      __builtin_amdgcn_s_setprio(0);
    }
    if (pf) { STB(nt, nb, 0); STB(nt, nb, 1); }
    {
      bf16x8 b1[2];
#pragma unroll
      for (int ks = 0; ks < 2; ++ks)
        b1[ks] = *(const bf16x8*)(B + (wr * 64 + 1 * 16 + (lane & 15)) * 128 +
                                  ((ks * 64 + kcol) ^ rsw));
      __builtin_amdgcn_s_setprio(1);
#pragma unroll
      for (int ks = 0; ks < 2; ++ks)
#pragma unroll
        for (int mf = 0; mf < 4; ++mf)
          acc[mf][1] = __builtin_amdgcn_mfma_f32_16x16x32_bf16(a[mf][ks], b1[ks],
                                                               acc[mf][1], 0, 0, 0);
      __builtin_amdgcn_s_setprio(0);
    }
    if (pf) { STB(nt, nb, 2); STB(nt, nb, 3); }
    {
      bf16x8 b2[2];
#pragma unroll
      for (int ks = 0; ks < 2; ++ks)
        b2[ks] = *(const bf16x8*)(B + (wr * 64 + 2 * 16 + (lane & 15)) * 128 +
                                  ((ks * 64 + kcol) ^ rsw));
      __builtin_amdgcn_s_setprio(1);
#pragma unroll
      for (int ks = 0; ks < 2; ++ks)
#pragma unroll
        for (int mf = 0; mf < 4; ++mf)
          acc[mf][2] = __builtin_amdgcn_mfma_f32_16x16x32_bf16(a[mf][ks], b2[ks],
                                                               acc[mf][2], 0, 0, 0);
      __builtin_amdgcn_s_setprio(0);
    }
    {
      bf16x8 b3[2];
#pragma unroll
      for (int ks = 0; ks < 2; ++ks)
        b3[ks] = *(const bf16x8*)(B + (wr * 64 + 3 * 16 + (lane & 15)) * 128 +
                                  ((ks * 64 + kcol) ^ rsw));
      __builtin_amdgcn_s_setprio(1);
#pragma unroll
      for (int ks = 0; ks < 2; ++ks)
#pragma unroll
        for (int mf = 0; mf < 4; ++mf)
          acc[mf][3] = __builtin_amdgcn_mfma_f32_16x16x32_bf16(a[mf][ks], b3[ks],
                                                               acc[mf][3], 0, 0, 0);
      __builtin_amdgcn_s_setprio(0);
    }
  };

  for (int t = 0; t < 15; ++t) {
    asm volatile("s_waitcnt vmcnt(6)" ::: "memory");
    __builtin_amdgcn_s_barrier();
    asm volatile("" ::: "memory");
    const char* A = lds + (t % 3) * LDSBUF;
    ktile(A, A + 16384, t + 2, (t + 2) % 3, t < 14);
  }
  asm volatile("s_waitcnt vmcnt(0)" ::: "memory");
  __builtin_amdgcn_s_barrier();
  asm volatile("" ::: "memory");
  {
    const char* A = lds + (15 % 3) * LDSBUF;
    ktile(A, A + 16384, 0, 0, false);
  }

  __syncthreads();
  float* mm = (float*)lds;
  float* zz = mm + 512;
  float* sv = zz + 512;
#pragma unroll
  for (int nf = 0; nf < 4; ++nf) {
    float m1 = -1e30f;
#pragma unroll
    for (int mf = 0; mf < 4; ++mf)
#pragma unroll
      for (int q = 0; q < 4; ++q) m1 = fmaxf(m1, acc[mf][nf][q]);
    m1 = fmaxf(m1, __shfl_xor(m1, 16));
    m1 = fmaxf(m1, __shfl_xor(m1, 32));
    float z1 = 0.f, s1 = 0.f;
#pragma unroll
    for (int mf = 0; mf < 4; ++mf)
#pragma unroll
      for (int q = 0; q < 4; ++q) {
        float tt = acc[mf][nf][q] - m1;
        float e = expf(tt);
        z1 += e;
        s1 += e * tt;
      }
    z1 += __shfl_xor(z1, 16); z1 += __shfl_xor(z1, 32);
    s1 += __shfl_xor(s1, 16); s1 += __shfl_xor(s1, 32);
    if (lane < 16) {
      int r = wr * 64 + nf * 16 + lane;
      mm[wc * 256 + r] = m1;
      zz[wc * 256 + r] = z1;
      sv[wc * 256 + r] = s1;
    }
  }
  __syncthreads();
  if (tid < 256) {
    float m0 = mm[tid], mA = mm[256 + tid];
    float z0 = zz[tid], zA = zz[256 + tid];
    float s0 = sv[tid], sA = sv[256 + tid];
    float M = fmaxf(m0, mA);
    float e0 = expf(m0 - M), e1 = expf(mA - M);
    float Z = z0 * e0 + zA * e1;
    float S = e0 * (s0 + (m0 - M) * z0) + e1 * (sA + (mA - M) * zA);
    size_t o = (size_t)cb * 8192 + R0 + tid;
    pm[o] = M;
    pz[o] = Z;
    ps[o] = S;
  }
}

// ---------------------------------------------------------------------------
// K4: parallel merge (R2-proven): 2048 blocks x 256 thr, one wave per row.
// loss = merge(8 partials); weight = dot(xbf_row, s) * rnorm / B.
// ---------------------------------------------------------------------------
__global__ __launch_bounds__(256) void k4_final(const unsigned short* __restrict__ xbf,
                                                const float* __restrict__ s,
                                                const float* __restrict__ rnorm,
                                                const float* __restrict__ pm,
                                                const float* __restrict__ pz,
                                                const float* __restrict__ ps,
                                                float* __restrict__ out) {
  int tid = threadIdx.x;
  int wid = tid >> 6, lane = tid & 63;
  int row = blockIdx.x * 4 + wid;
  const bf16x8* xr = (const bf16x8*)(xbf + (size_t)row * 1024);
  const float4* s4 = (const float4*)s;
  float dot = 0.f;
#pragma unroll
  for (int j = 0; j < 2; ++j) {
    bf16x8 v = xr[lane + j * 64];
    float4 sa = s4[(lane + j * 64) * 2];
    float4 sb = s4[(lane + j * 64) * 2 + 1];
    dot += bf2f((unsigned short)v[0]) * sa.x + bf2f((unsigned short)v[1]) * sa.y +
           bf2f((unsigned short)v[2]) * sa.z + bf2f((unsigned short)v[3]) * sa.w +
           bf2f((unsigned short)v[4]) * sb.x + bf2f((unsigned short)v[5]) * sb.y +
           bf2f((unsigned short)v[6]) * sb.z + bf2f((unsigned short)v[7]) * sb.w;
  }
#pragma unroll
  for (int m = 1; m < 64; m <<= 1) dot += __shfl_xor(dot, m);
  if (lane == 0) {
    float mv[8], zv[8], svv[8];
    float M = -1e30f;
#pragma unroll
    for (int c = 0; c < 8; ++c) {
      mv[c] = pm[(size_t)c * 8192 + row];
      zv[c] = pz[(size_t)c * 8192 + row];
      svv[c] = ps[(size_t)c * 8192 + row];
      M = fmaxf(M, mv[c]);
    }
    float Z = 0.f, S = 0.f;
#pragma unroll
    for (int c = 0; c < 8; ++c) {
      float e = expf(mv[c] - M);
      Z += zv[c] * e;
      S += e * (svv[c] + (mv[c] - M) * zv[c]);
    }
    float loss = S / Z - logf(Z);
    out[row] = loss * dot * rnorm[row] * (1.f / 8192.f);
  }
}

// ---------------------------------------------------------------------------
extern "C" void kernel_launch(void* const* d_in, const int* in_sizes, int n_in,
                              void* d_out, int out_size, void* d_ws, size_t ws_size,
                              hipStream_t stream) {
  (void)in_sizes; (void)n_in; (void)out_size; (void)ws_size;
  const float* x = (const float*)d_in[0];
  const float* W = (const float*)d_in[1];
  const float* b = (const float*)d_in[2];
  float* out = (float*)d_out;
  char* ws = (char*)d_ws;

  unsigned short* Wt = (unsigned short*)(ws + 0);           // 2 MiB
  unsigned short* xbf = (unsigned short*)(ws + 2097152);    // 16 MiB
  float* rnorm = (float*)(ws + 18874368);                   // 32 KiB
  float* s = (float*)(ws + 18907136);                       // 4 KiB
  float* pm = (float*)(ws + 18915328);                      // 256 KiB
  float* pz = (float*)(ws + 18915328 + 262144);
  float* ps = (float*)(ws + 18915328 + 524288);

  hipMemsetAsync(s, 0, 4096, stream);
  k01_prep<<<256, 512, 0, stream>>>(W, Wt, x, xbf, rnorm, s);
  k3_gemm<<<256, 512, 0, stream>>>(xbf, Wt, b, pm, pz, ps);
  k4_final<<<2048, 256, 0, stream>>>(xbf, s, rnorm, pm, pz, ps, out);
}

// Round 13
// 52.236 us; speedup vs baseline: 1.6148x; 1.0176x over previous
//
#include <hip/hip_runtime.h>
#include <hip/hip_bf16.h>
#include <cstdint>
#include <cstddef>

typedef __attribute__((ext_vector_type(8))) short bf16x8;
typedef __attribute__((ext_vector_type(4))) float f32x4;

__device__ __forceinline__ unsigned short f2bf(float f) {
  union { float f; unsigned u; } v; v.f = f;
  unsigned r = v.u + 0x7FFFu + ((v.u >> 16) & 1u);
  return (unsigned short)(r >> 16);
}

__device__ __forceinline__ float bf2f(unsigned short h) {
  union { float f; unsigned u; } c; c.u = ((unsigned)h) << 16;
  return c.f;
}

__device__ __forceinline__ void gload_lds16(const void* g, void* l) {
  __builtin_amdgcn_global_load_lds(
      (const __attribute__((address_space(1))) unsigned int*)g,
      (__attribute__((address_space(3))) unsigned int*)l, 16, 0, 0);
}

// ---------------------------------------------------------------------------
// K01 v3: 256 blocks x 1024 thr (16 waves/CU = 4 waves/SIMD, 2x R12's TLP).
// Phase (a): 64x64 W-transpose tile (1024 thr, 4 elems each).
// Phase (b): 32 x-rows, 2 rows/wave with both rows' loads issued up-front
// (2x ILP); s block-reduce via 16-wave LDS tree (64KB, reuses tile region
// after barrier); one device atomicAdd per address per block (256-deep
// chains, unchanged).
// ---------------------------------------------------------------------------
__global__ __launch_bounds__(1024) void k01_prep(const float* __restrict__ W,
                                                 unsigned short* __restrict__ Wt,
                                                 const float* __restrict__ x,
                                                 unsigned short* __restrict__ xbf,
                                                 float* __restrict__ rnorm,
                                                 float* __restrict__ s) {
  __shared__ __align__(16) char sm[65536];  // tile 16.7KB (phase a) | sblk 64KB (phase b)
  int tid = threadIdx.x;
  int b = blockIdx.x;
  int lane = tid & 63;
  int wid = tid >> 6;  // 0..15

  // (a) W transpose tile: k [k0,k0+64), cls [c0,c0+64)
  {
    float (*tile)[65] = (float(*)[65])sm;
    int k0 = (b & 15) * 64;
    int c0 = (b >> 4) * 64;
    int tx = tid & 63;
    int ty = tid >> 6;  // 0..15
#pragma unroll
    for (int i = 0; i < 4; ++i) {
      int r = i * 16 + ty;
      int c = c0 + tx;
      tile[r][tx] = (c < 1000) ? W[(size_t)(k0 + r) * 1000 + c] : 0.f;
    }
    __syncthreads();
#pragma unroll
    for (int i = 0; i < 4; ++i) {
      int ct = i * 16 + ty;
      Wt[(size_t)(c0 + ct) * 1024 + (k0 + tx)] = f2bf(tile[tx][ct]);
    }
    __syncthreads();  // tile region about to be reused as sblk
  }

  // (b) norm/convert rows [32b, 32b+32): wave w owns rows w*2, w*2+1
  {
    float (*sblk)[1024] = (float(*)[1024])sm;
    int row0 = b * 32 + wid * 2;
    const float4* xr0 = (const float4*)(x + (size_t)row0 * 1024);
    const float4* xr1 = (const float4*)(x + (size_t)(row0 + 1) * 1024);
    float4 v[2][4];
    // all 8 loads issued before any reduction (ILP)
#pragma unroll
    for (int j = 0; j < 4; ++j) v[0][j] = xr0[lane + j * 64];
#pragma unroll
    for (int j = 0; j < 4; ++j) v[1][j] = xr1[lane + j * 64];
    float ss0 = 0.f, ss1 = 0.f;
#pragma unroll
    for (int j = 0; j < 4; ++j) {
      ss0 += v[0][j].x * v[0][j].x + v[0][j].y * v[0][j].y +
             v[0][j].z * v[0][j].z + v[0][j].w * v[0][j].w;
      ss1 += v[1][j].x * v[1][j].x + v[1][j].y * v[1][j].y +
             v[1][j].z * v[1][j].z + v[1][j].w * v[1][j].w;
    }
#pragma unroll
    for (int m = 1; m < 64; m <<= 1) {
      ss0 += __shfl_xor(ss0, m);
      ss1 += __shfl_xor(ss1, m);
    }
    float rn0 = 1.f / fmaxf(sqrtf(ss0), 1e-8f);
    float rn1 = 1.f / fmaxf(sqrtf(ss1), 1e-8f);
    if (lane == 0) {
      rnorm[row0] = rn0;
      rnorm[row0 + 1] = rn1;
    }
    float4 sacc[4];
#pragma unroll
    for (int j = 0; j < 4; ++j) {
      ushort4 h0, h1;
      h0.x = f2bf(v[0][j].x); h0.y = f2bf(v[0][j].y);
      h0.z = f2bf(v[0][j].z); h0.w = f2bf(v[0][j].w);
      h1.x = f2bf(v[1][j].x); h1.y = f2bf(v[1][j].y);
      h1.z = f2bf(v[1][j].z); h1.w = f2bf(v[1][j].w);
      ((ushort4*)(xbf + (size_t)row0 * 1024))[lane + j * 64] = h0;
      ((ushort4*)(xbf + (size_t)(row0 + 1) * 1024))[lane + j * 64] = h1;
      sacc[j].x = v[0][j].x * rn0 + v[1][j].x * rn1;
      sacc[j].y = v[0][j].y * rn0 + v[1][j].y * rn1;
      sacc[j].z = v[0][j].z * rn0 + v[1][j].z * rn1;
      sacc[j].w = v[0][j].w * rn0 + v[1][j].w * rn1;
    }
#pragma unroll
    for (int j = 0; j < 4; ++j) ((float4*)sblk[wid])[j * 64 + lane] = sacc[j];
    __syncthreads();
    // d = tid (1024 threads, exactly one address each)
    float t = 0.f;
#pragma unroll
    for (int w = 0; w < 16; ++w) t += sblk[w][tid];
    atomicAdd(&s[tid], t);
  }
}

// ---------------------------------------------------------------------------
// K3: pure GEMM + softmax partials (R12-proven, byte-identical). Tri-buffer,
// depth-2 prefetch, counted vmcnt(6), XOR-swizzle, XCD-aligned cb=b>>5,
// rb=b&31.
// ---------------------------------------------------------------------------
#define LDSBUF 49152

__global__ __launch_bounds__(512) void k3_gemm(const unsigned short* __restrict__ xbf,
                                               const unsigned short* __restrict__ wt,
                                               const float* __restrict__ bias,
                                               float* __restrict__ pm,
                                               float* __restrict__ pz,
                                               float* __restrict__ ps) {
  __shared__ __align__(16) char lds[147456];

  int tid = threadIdx.x;
  int lane = tid & 63;
  int wid = tid >> 6;
  int wc = wid & 1;
  int wr = wid >> 1;
  int cb = blockIdx.x >> 5;
  int rb = blockIdx.x & 31;
  int C0 = cb * 128;
  int R0 = rb * 256;

  float bv[4][4];
#pragma unroll
  for (int mf = 0; mf < 4; ++mf)
#pragma unroll
    for (int q = 0; q < 4; ++q) {
      int cls_g = C0 + wc * 64 + mf * 16 + (lane >> 4) * 4 + q;
      bv[mf][q] = (cls_g < 1000) ? bias[cls_g] : -1e30f;
    }
  f32x4 acc[4][4];
#pragma unroll
  for (int mf = 0; mf < 4; ++mf)
#pragma unroll
    for (int nf = 0; nf < 4; ++nf)
#pragma unroll
      for (int q = 0; q < 4; ++q) acc[mf][nf][q] = bv[mf][q];

  const char* gA = (const char*)(wt + (size_t)C0 * 1024);
  const char* gB = (const char*)(xbf + (size_t)R0 * 1024);
  int grow = lane >> 3;
  int gswz = ((lane & 7) ^ grow) << 4;

#define STA(kt, b, r)                                                          \
  gload_lds16(gA + (size_t)((r) * 64 + wid * 8 + grow) * 2048 + (kt) * 128 +   \
                  gswz,                                                        \
              lds + (b) * LDSBUF + (r) * 8192 + wid * 1024)
#define STB(kt, b, r)                                                          \
  gload_lds16(gB + (size_t)((r) * 64 + wid * 8 + grow) * 2048 + (kt) * 128 +   \
                  gswz,                                                        \
              lds + (b) * LDSBUF + 16384 + (r) * 8192 + wid * 1024)

  STA(0, 0, 0); STA(0, 0, 1); STB(0, 0, 0); STB(0, 0, 1); STB(0, 0, 2); STB(0, 0, 3);
  STA(1, 1, 0); STA(1, 1, 1); STB(1, 1, 0); STB(1, 1, 1); STB(1, 1, 2); STB(1, 1, 3);

  int rsw = (lane & 7) << 4;
  int kcol = (lane >> 4) * 16;

  auto ktile = [&](const char* A, const char* B, int nt, int nb, bool pf) {
    if (pf) { STA(nt, nb, 0); STA(nt, nb, 1); }
    bf16x8 a[4][2];
#pragma unroll
    for (int mf = 0; mf < 4; ++mf)
#pragma unroll
      for (int ks = 0; ks < 2; ++ks)
        a[mf][ks] = *(const bf16x8*)(A + (wc * 64 + mf * 16 + (lane & 15)) * 128 +
                                     ((ks * 64 + kcol) ^ rsw));
    {
      bf16x8 b0[2];
#pragma unroll
      for (int ks = 0; ks < 2; ++ks)
        b0[ks] = *(const bf16x8*)(B + (wr * 64 + 0 * 16 + (lane & 15)) * 128 +
                                  ((ks * 64 + kcol) ^ rsw));
      __builtin_amdgcn_s_setprio(1);
#pragma unroll
      for (int ks = 0; ks < 2; ++ks)
#pragma unroll
        for (int mf = 0; mf < 4; ++mf)
          acc[mf][0] = __builtin_amdgcn_mfma_f32_16x16x32_bf16(a[mf][ks], b0[ks],
                                                               acc[mf][0], 0, 0, 0);
      __builtin_amdgcn_s_setprio(0);
    }
    if (pf) { STB(nt, nb, 0); STB(nt, nb, 1); }
    {
      bf16x8 b1[2];
#pragma unroll
      for (int ks = 0; ks < 2; ++ks)
        b1[ks] = *(const bf16x8*)(B + (wr * 64 + 1 * 16 + (lane & 15)) * 128 +
                                  ((ks * 64 + kcol) ^ rsw));
      __builtin_amdgcn_s_setprio(1);
#pragma unroll
      for (int ks = 0; ks < 2; ++ks)
#pragma unroll
        for (int mf = 0; mf < 4; ++mf)
          acc[mf][1] = __builtin_amdgcn_mfma_f32_16x16x32_bf16(a[mf][ks], b1[ks],
                                                               acc[mf][1], 0, 0, 0);
      __builtin_amdgcn_s_setprio(0);
    }
    if (pf) { STB(nt, nb, 2); STB(nt, nb, 3); }
    {
      bf16x8 b2[2];
#pragma unroll
      for (int ks = 0; ks < 2; ++ks)
        b2[ks] = *(const bf16x8*)(B + (wr * 64 + 2 * 16 + (lane & 15)) * 128 +
                                  ((ks * 64 + kcol) ^ rsw));
      __builtin_amdgcn_s_setprio(1);
#pragma unroll
      for (int ks = 0; ks < 2; ++ks)
#pragma unroll
        for (int mf = 0; mf < 4; ++mf)
          acc[mf][2] = __builtin_amdgcn_mfma_f32_16x16x32_bf16(a[mf][ks], b2[ks],
                                                               acc[mf][2], 0, 0, 0);
      __builtin_amdgcn_s_setprio(0);
    }
    {
      bf16x8 b3[2];
#pragma unroll
      for (int ks = 0; ks < 2; ++ks)
        b3[ks] = *(const bf16x8*)(B + (wr * 64 + 3 * 16 + (lane & 15)) * 128 +
                                  ((ks * 64 + kcol) ^ rsw));
      __builtin_amdgcn_s_setprio(1);
#pragma unroll
      for (int ks = 0; ks < 2; ++ks)
#pragma unroll
        for (int mf = 0; mf < 4; ++mf)
          acc[mf][3] = __builtin_amdgcn_mfma_f32_16x16x32_bf16(a[mf][ks], b3[ks],
                                                               acc[mf][3], 0, 0, 0);
      __builtin_amdgcn_s_setprio(0);
    }
  };

  for (int t = 0; t < 15; ++t) {
    asm volatile("s_waitcnt vmcnt(6)" ::: "memory");
    __builtin_amdgcn_s_barrier();
    asm volatile("" ::: "memory");
    const char* A = lds + (t % 3) * LDSBUF;
    ktile(A, A + 16384, t + 2, (t + 2) % 3, t < 14);
  }
  asm volatile("s_waitcnt vmcnt(0)" ::: "memory");
  __builtin_amdgcn_s_barrier();
  asm volatile("" ::: "memory");
  {
    const char* A = lds + (15 % 3) * LDSBUF;
    ktile(A, A + 16384, 0, 0, false);
  }

  __syncthreads();
  float* mm = (float*)lds;
  float* zz = mm + 512;
  float* sv = zz + 512;
#pragma unroll
  for (int nf = 0; nf < 4; ++nf) {
    float m1 = -1e30f;
#pragma unroll
    for (int mf = 0; mf < 4; ++mf)
#pragma unroll
      for (int q = 0; q < 4; ++q) m1 = fmaxf(m1, acc[mf][nf][q]);
    m1 = fmaxf(m1, __shfl_xor(m1, 16));
    m1 = fmaxf(m1, __shfl_xor(m1, 32));
    float z1 = 0.f, s1 = 0.f;
#pragma unroll
    for (int mf = 0; mf < 4; ++mf)
#pragma unroll
      for (int q = 0; q < 4; ++q) {
        float tt = acc[mf][nf][q] - m1;
        float e = expf(tt);
        z1 += e;
        s1 += e * tt;
      }
    z1 += __shfl_xor(z1, 16); z1 += __shfl_xor(z1, 32);
    s1 += __shfl_xor(s1, 16); s1 += __shfl_xor(s1, 32);
    if (lane < 16) {
      int r = wr * 64 + nf * 16 + lane;
      mm[wc * 256 + r] = m1;
      zz[wc * 256 + r] = z1;
      sv[wc * 256 + r] = s1;
    }
  }
  __syncthreads();
  if (tid < 256) {
    float m0 = mm[tid], mA = mm[256 + tid];
    float z0 = zz[tid], zA = zz[256 + tid];
    float s0 = sv[tid], sA = sv[256 + tid];
    float M = fmaxf(m0, mA);
    float e0 = expf(m0 - M), e1 = expf(mA - M);
    float Z = z0 * e0 + zA * e1;
    float S = e0 * (s0 + (m0 - M) * z0) + e1 * (sA + (mA - M) * zA);
    size_t o = (size_t)cb * 8192 + R0 + tid;
    pm[o] = M;
    pz[o] = Z;
    ps[o] = S;
  }
}

// ---------------------------------------------------------------------------
// K4: parallel merge (R12-proven): 2048 blocks x 256 thr, one wave per row.
// ---------------------------------------------------------------------------
__global__ __launch_bounds__(256) void k4_final(const unsigned short* __restrict__ xbf,
                                                const float* __restrict__ s,
                                                const float* __restrict__ rnorm,
                                                const float* __restrict__ pm,
                                                const float* __restrict__ pz,
                                                const float* __restrict__ ps,
                                                float* __restrict__ out) {
  int tid = threadIdx.x;
  int wid = tid >> 6, lane = tid & 63;
  int row = blockIdx.x * 4 + wid;
  const bf16x8* xr = (const bf16x8*)(xbf + (size_t)row * 1024);
  const float4* s4 = (const float4*)s;
  float dot = 0.f;
#pragma unroll
  for (int j = 0; j < 2; ++j) {
    bf16x8 v = xr[lane + j * 64];
    float4 sa = s4[(lane + j * 64) * 2];
    float4 sb = s4[(lane + j * 64) * 2 + 1];
    dot += bf2f((unsigned short)v[0]) * sa.x + bf2f((unsigned short)v[1]) * sa.y +
           bf2f((unsigned short)v[2]) * sa.z + bf2f((unsigned short)v[3]) * sa.w +
           bf2f((unsigned short)v[4]) * sb.x + bf2f((unsigned short)v[5]) * sb.y +
           bf2f((unsigned short)v[6]) * sb.z + bf2f((unsigned short)v[7]) * sb.w;
  }
#pragma unroll
  for (int m = 1; m < 64; m <<= 1) dot += __shfl_xor(dot, m);
  if (lane == 0) {
    float mv[8], zv[8], svv[8];
    float M = -1e30f;
#pragma unroll
    for (int c = 0; c < 8; ++c) {
      mv[c] = pm[(size_t)c * 8192 + row];
      zv[c] = pz[(size_t)c * 8192 + row];
      svv[c] = ps[(size_t)c * 8192 + row];
      M = fmaxf(M, mv[c]);
    }
    float Z = 0.f, S = 0.f;
#pragma unroll
    for (int c = 0; c < 8; ++c) {
      float e = expf(mv[c] - M);
      Z += zv[c] * e;
      S += e * (svv[c] + (mv[c] - M) * zv[c]);
    }
    float loss = S / Z - logf(Z);
    out[row] = loss * dot * rnorm[row] * (1.f / 8192.f);
  }
}

// ---------------------------------------------------------------------------
extern "C" void kernel_launch(void* const* d_in, const int* in_sizes, int n_in,
                              void* d_out, int out_size, void* d_ws, size_t ws_size,
                              hipStream_t stream) {
  (void)in_sizes; (void)n_in; (void)out_size; (void)ws_size;
  const float* x = (const float*)d_in[0];
  const float* W = (const float*)d_in[1];
  const float* b = (const float*)d_in[2];
  float* out = (float*)d_out;
  char* ws = (char*)d_ws;

  unsigned short* Wt = (unsigned short*)(ws + 0);           // 2 MiB
  unsigned short* xbf = (unsigned short*)(ws + 2097152);    // 16 MiB
  float* rnorm = (float*)(ws + 18874368);                   // 32 KiB
  float* s = (float*)(ws + 18907136);                       // 4 KiB
  float* pm = (float*)(ws + 18915328);                      // 256 KiB
  float* pz = (float*)(ws + 18915328 + 262144);
  float* ps = (float*)(ws + 18915328 + 524288);

  hipMemsetAsync(s, 0, 4096, stream);
  k01_prep<<<256, 1024, 0, stream>>>(W, Wt, x, xbf, rnorm, s);
  k3_gemm<<<256, 512, 0, stream>>>(xbf, Wt, b, pm, pz, ps);
  k4_final<<<2048, 256, 0, stream>>>(xbf, s, rnorm, pm, pz, ps, out);
}

// Round 14
// 52.223 us; speedup vs baseline: 1.6152x; 1.0002x over previous
//
#include <hip/hip_runtime.h>
#include <hip/hip_bf16.h>
#include <cstdint>
#include <cstddef>

typedef __attribute__((ext_vector_type(8))) short bf16x8;
typedef __attribute__((ext_vector_type(4))) float f32x4;

__device__ __forceinline__ unsigned short f2bf(float f) {
  union { float f; unsigned u; } v; v.f = f;
  unsigned r = v.u + 0x7FFFu + ((v.u >> 16) & 1u);
  return (unsigned short)(r >> 16);
}

__device__ __forceinline__ float bf2f(unsigned short h) {
  union { float f; unsigned u; } c; c.u = ((unsigned)h) << 16;
  return c.f;
}

__device__ __forceinline__ void gload_lds16(const void* g, void* l) {
  __builtin_amdgcn_global_load_lds(
      (const __attribute__((address_space(1))) unsigned int*)g,
      (__attribute__((address_space(3))) unsigned int*)l, 16, 0, 0);
}

// ---------------------------------------------------------------------------
// K01 v4: 256 blocks x 1024 thr. W-tile loads HOISTED into registers before
// the x-phase (HBM latency hides under the 9us x stream); transpose via LDS
// at the end; disjoint LDS regions (sblk 64KB @0, tile 16.7KB @65536) so no
// phase serialization; s-atomics issue before the transpose tail.
// ---------------------------------------------------------------------------
__global__ __launch_bounds__(1024) void k01_prep(const float* __restrict__ W,
                                                 unsigned short* __restrict__ Wt,
                                                 const float* __restrict__ x,
                                                 unsigned short* __restrict__ xbf,
                                                 float* __restrict__ rnorm,
                                                 float* __restrict__ s) {
  __shared__ __align__(16) char sm[82176];
  int tid = threadIdx.x;
  int b = blockIdx.x;
  int lane = tid & 63;
  int wid = tid >> 6;  // 0..15

  // (1) issue W loads early (regs), consumed at the end
  int k0 = (b & 15) * 64;
  int c0 = (b >> 4) * 64;
  int tx = tid & 63;
  int ty = tid >> 6;  // 0..15
  float wreg[4];
#pragma unroll
  for (int i = 0; i < 4; ++i) {
    int c = c0 + tx;
    wreg[i] = (c < 1000) ? W[(size_t)(k0 + i * 16 + ty) * 1000 + c] : 0.f;
  }

  // (2) x phase: rows [32b, 32b+32), 2 rows/wave, loads up-front
  {
    float (*sblk)[1024] = (float(*)[1024])sm;
    int row0 = b * 32 + wid * 2;
    const float4* xr0 = (const float4*)(x + (size_t)row0 * 1024);
    const float4* xr1 = (const float4*)(x + (size_t)(row0 + 1) * 1024);
    float4 v[2][4];
#pragma unroll
    for (int j = 0; j < 4; ++j) v[0][j] = xr0[lane + j * 64];
#pragma unroll
    for (int j = 0; j < 4; ++j) v[1][j] = xr1[lane + j * 64];
    float ss0 = 0.f, ss1 = 0.f;
#pragma unroll
    for (int j = 0; j < 4; ++j) {
      ss0 += v[0][j].x * v[0][j].x + v[0][j].y * v[0][j].y +
             v[0][j].z * v[0][j].z + v[0][j].w * v[0][j].w;
      ss1 += v[1][j].x * v[1][j].x + v[1][j].y * v[1][j].y +
             v[1][j].z * v[1][j].z + v[1][j].w * v[1][j].w;
    }
#pragma unroll
    for (int m = 1; m < 64; m <<= 1) {
      ss0 += __shfl_xor(ss0, m);
      ss1 += __shfl_xor(ss1, m);
    }
    float rn0 = 1.f / fmaxf(sqrtf(ss0), 1e-8f);
    float rn1 = 1.f / fmaxf(sqrtf(ss1), 1e-8f);
    if (lane == 0) {
      rnorm[row0] = rn0;
      rnorm[row0 + 1] = rn1;
    }
    float4 sacc[4];
#pragma unroll
    for (int j = 0; j < 4; ++j) {
      ushort4 h0, h1;
      h0.x = f2bf(v[0][j].x); h0.y = f2bf(v[0][j].y);
      h0.z = f2bf(v[0][j].z); h0.w = f2bf(v[0][j].w);
      h1.x = f2bf(v[1][j].x); h1.y = f2bf(v[1][j].y);
      h1.z = f2bf(v[1][j].z); h1.w = f2bf(v[1][j].w);
      ((ushort4*)(xbf + (size_t)row0 * 1024))[lane + j * 64] = h0;
      ((ushort4*)(xbf + (size_t)(row0 + 1) * 1024))[lane + j * 64] = h1;
      sacc[j].x = v[0][j].x * rn0 + v[1][j].x * rn1;
      sacc[j].y = v[0][j].y * rn0 + v[1][j].y * rn1;
      sacc[j].z = v[0][j].z * rn0 + v[1][j].z * rn1;
      sacc[j].w = v[0][j].w * rn0 + v[1][j].w * rn1;
    }
#pragma unroll
    for (int j = 0; j < 4; ++j) ((float4*)sblk[wid])[j * 64 + lane] = sacc[j];
    __syncthreads();
    float t = 0.f;
#pragma unroll
    for (int w = 0; w < 16; ++w) t += sblk[w][tid];
    atomicAdd(&s[tid], t);  // drains under the transpose below
  }

  // (3) W transpose via dedicated LDS region
  {
    float (*tile)[65] = (float(*)[65])(sm + 65536);
#pragma unroll
    for (int i = 0; i < 4; ++i) tile[i * 16 + ty][tx] = wreg[i];
    __syncthreads();
#pragma unroll
    for (int i = 0; i < 4; ++i) {
      int ct = i * 16 + ty;
      Wt[(size_t)(c0 + ct) * 1024 + (k0 + tx)] = f2bf(tile[tx][ct]);
    }
  }
}

// ---------------------------------------------------------------------------
// K3: GEMM + softmax partials, now with the TRUE phase-barrier schedule
// (T3): per K-tile 4 phases, each {ds_read frags || issue staging ->
// s_barrier -> setprio(1) -> 8 MFMA -> setprio(0) -> s_barrier}. 8 barriers
// per K-tile (m201 density). Tri-buffer, depth-2 prefetch, counted vmcnt(6),
// XOR-swizzle, XCD-aligned cb=b>>5 / rb=b&31 all unchanged.
// Write-safety: staging targets buf[(t+2)%3], last read in tile t-1; every
// wave passed tile t-1's final barrier (post-MFMA, post-lgkm) before any
// wave can issue tile t's staging.
// ---------------------------------------------------------------------------
#define LDSBUF 49152

__global__ __launch_bounds__(512) void k3_gemm(const unsigned short* __restrict__ xbf,
                                               const unsigned short* __restrict__ wt,
                                               const float* __restrict__ bias,
                                               float* __restrict__ pm,
                                               float* __restrict__ pz,
                                               float* __restrict__ ps) {
  __shared__ __align__(16) char lds[147456];

  int tid = threadIdx.x;
  int lane = tid & 63;
  int wid = tid >> 6;
  int wc = wid & 1;
  int wr = wid >> 1;
  int cb = blockIdx.x >> 5;
  int rb = blockIdx.x & 31;
  int C0 = cb * 128;
  int R0 = rb * 256;

  float bv[4][4];
#pragma unroll
  for (int mf = 0; mf < 4; ++mf)
#pragma unroll
    for (int q = 0; q < 4; ++q) {
      int cls_g = C0 + wc * 64 + mf * 16 + (lane >> 4) * 4 + q;
      bv[mf][q] = (cls_g < 1000) ? bias[cls_g] : -1e30f;
    }
  f32x4 acc[4][4];
#pragma unroll
  for (int mf = 0; mf < 4; ++mf)
#pragma unroll
    for (int nf = 0; nf < 4; ++nf)
#pragma unroll
      for (int q = 0; q < 4; ++q) acc[mf][nf][q] = bv[mf][q];

  const char* gA = (const char*)(wt + (size_t)C0 * 1024);
  const char* gB = (const char*)(xbf + (size_t)R0 * 1024);
  int grow = lane >> 3;
  int gswz = ((lane & 7) ^ grow) << 4;

#define STA(kt, b, r)                                                          \
  gload_lds16(gA + (size_t)((r) * 64 + wid * 8 + grow) * 2048 + (kt) * 128 +   \
                  gswz,                                                        \
              lds + (b) * LDSBUF + (r) * 8192 + wid * 1024)
#define STB(kt, b, r)                                                          \
  gload_lds16(gB + (size_t)((r) * 64 + wid * 8 + grow) * 2048 + (kt) * 128 +   \
                  gswz,                                                        \
              lds + (b) * LDSBUF + 16384 + (r) * 8192 + wid * 1024)

  STA(0, 0, 0); STA(0, 0, 1); STB(0, 0, 0); STB(0, 0, 1); STB(0, 0, 2); STB(0, 0, 3);
  STA(1, 1, 0); STA(1, 1, 1); STB(1, 1, 0); STB(1, 1, 1); STB(1, 1, 2); STB(1, 1, 3);

  int rsw = (lane & 7) << 4;
  int kcol = (lane >> 4) * 16;

  // one phase: ds_read b-frags (+a at p0) || staging -> bar -> MFMA -> bar
  auto ktile = [&](const char* A, const char* B, int nt, int nb, bool pf) {
    bf16x8 a[4][2];
    // ---- P0 ----
#pragma unroll
    for (int mf = 0; mf < 4; ++mf)
#pragma unroll
      for (int ks = 0; ks < 2; ++ks)
        a[mf][ks] = *(const bf16x8*)(A + (wc * 64 + mf * 16 + (lane & 15)) * 128 +
                                     ((ks * 64 + kcol) ^ rsw));
    {
      bf16x8 b0[2];
#pragma unroll
      for (int ks = 0; ks < 2; ++ks)
        b0[ks] = *(const bf16x8*)(B + (wr * 64 + 0 * 16 + (lane & 15)) * 128 +
                                  ((ks * 64 + kcol) ^ rsw));
      if (pf) { STA(nt, nb, 0); STA(nt, nb, 1); }
      __builtin_amdgcn_s_barrier();
      __builtin_amdgcn_s_setprio(1);
#pragma unroll
      for (int ks = 0; ks < 2; ++ks)
#pragma unroll
        for (int mf = 0; mf < 4; ++mf)
          acc[mf][0] = __builtin_amdgcn_mfma_f32_16x16x32_bf16(a[mf][ks], b0[ks],
                                                               acc[mf][0], 0, 0, 0);
      __builtin_amdgcn_s_setprio(0);
      __builtin_amdgcn_s_barrier();
    }
    // ---- P1 ----
    {
      bf16x8 b1[2];
#pragma unroll
      for (int ks = 0; ks < 2; ++ks)
        b1[ks] = *(const bf16x8*)(B + (wr * 64 + 1 * 16 + (lane & 15)) * 128 +
                                  ((ks * 64 + kcol) ^ rsw));
      if (pf) { STB(nt, nb, 0); STB(nt, nb, 1); }
      __builtin_amdgcn_s_barrier();
      __builtin_amdgcn_s_setprio(1);
#pragma unroll
      for (int ks = 0; ks < 2; ++ks)
#pragma unroll
        for (int mf = 0; mf < 4; ++mf)
          acc[mf][1] = __builtin_amdgcn_mfma_f32_16x16x32_bf16(a[mf][ks], b1[ks],
                                                               acc[mf][1], 0, 0, 0);
      __builtin_amdgcn_s_setprio(0);
      __builtin_amdgcn_s_barrier();
    }
    // ---- P2 ----
    {
      bf16x8 b2[2];
#pragma unroll
      for (int ks = 0; ks < 2; ++ks)
        b2[ks] = *(const bf16x8*)(B + (wr * 64 + 2 * 16 + (lane & 15)) * 128 +
                                  ((ks * 64 + kcol) ^ rsw));
      if (pf) { STB(nt, nb, 2); STB(nt, nb, 3); }
      __builtin_amdgcn_s_barrier();
      __builtin_amdgcn_s_setprio(1);
#pragma unroll
      for (int ks = 0; ks < 2; ++ks)
#pragma unroll
        for (int mf = 0; mf < 4; ++mf)
          acc[mf][2] = __builtin_amdgcn_mfma_f32_16x16x32_bf16(a[mf][ks], b2[ks],
                                                               acc[mf][2], 0, 0, 0);
      __builtin_amdgcn_s_setprio(0);
      __builtin_amdgcn_s_barrier();
    }
    // ---- P3 (no trailing barrier: loop head vmcnt+barrier covers it) ----
    {
      bf16x8 b3[2];
#pragma unroll
      for (int ks = 0; ks < 2; ++ks)
        b3[ks] = *(const bf16x8*)(B + (wr * 64 + 3 * 16 + (lane & 15)) * 128 +
                                  ((ks * 64 + kcol) ^ rsw));
      __builtin_amdgcn_s_barrier();
      __builtin_amdgcn_s_setprio(1);
#pragma unroll
      for (int ks = 0; ks < 2; ++ks)
#pragma unroll
        for (int mf = 0; mf < 4; ++mf)
          acc[mf][3] = __builtin_amdgcn_mfma_f32_16x16x32_bf16(a[mf][ks], b3[ks],
                                                               acc[mf][3], 0, 0, 0);
      __builtin_amdgcn_s_setprio(0);
    }
  };

  for (int t = 0; t < 15; ++t) {
    asm volatile("s_waitcnt vmcnt(6)" ::: "memory");
    __builtin_amdgcn_s_barrier();
    asm volatile("" ::: "memory");
    const char* A = lds + (t % 3) * LDSBUF;
    ktile(A, A + 16384, t + 2, (t + 2) % 3, t < 14);
  }
  asm volatile("s_waitcnt vmcnt(0)" ::: "memory");
  __builtin_amdgcn_s_barrier();
  asm volatile("" ::: "memory");
  {
    const char* A = lds + (15 % 3) * LDSBUF;
    ktile(A, A + 16384, 0, 0, false);
  }

  __syncthreads();
  float* mm = (float*)lds;
  float* zz = mm + 512;
  float* sv = zz + 512;
#pragma unroll
  for (int nf = 0; nf < 4; ++nf) {
    float m1 = -1e30f;
#pragma unroll
    for (int mf = 0; mf < 4; ++mf)
#pragma unroll
      for (int q = 0; q < 4; ++q) m1 = fmaxf(m1, acc[mf][nf][q]);
    m1 = fmaxf(m1, __shfl_xor(m1, 16));
    m1 = fmaxf(m1, __shfl_xor(m1, 32));
    float z1 = 0.f, s1 = 0.f;
#pragma unroll
    for (int mf = 0; mf < 4; ++mf)
#pragma unroll
      for (int q = 0; q < 4; ++q) {
        float tt = acc[mf][nf][q] - m1;
        float e = expf(tt);
        z1 += e;
        s1 += e * tt;
      }
    z1 += __shfl_xor(z1, 16); z1 += __shfl_xor(z1, 32);
    s1 += __shfl_xor(s1, 16); s1 += __shfl_xor(s1, 32);
    if (lane < 16) {
      int r = wr * 64 + nf * 16 + lane;
      mm[wc * 256 + r] = m1;
      zz[wc * 256 + r] = z1;
      sv[wc * 256 + r] = s1;
    }
  }
  __syncthreads();
  if (tid < 256) {
    float m0 = mm[tid], mA = mm[256 + tid];
    float z0 = zz[tid], zA = zz[256 + tid];
    float s0 = sv[tid], sA = sv[256 + tid];
    float M = fmaxf(m0, mA);
    float e0 = expf(m0 - M), e1 = expf(mA - M);
    float Z = z0 * e0 + zA * e1;
    float S = e0 * (s0 + (m0 - M) * z0) + e1 * (sA + (mA - M) * zA);
    size_t o = (size_t)cb * 8192 + R0 + tid;
    pm[o] = M;
    pz[o] = Z;
    ps[o] = S;
  }
}

// ---------------------------------------------------------------------------
// K4: parallel merge (R12-proven): 2048 blocks x 256 thr, one wave per row.
// ---------------------------------------------------------------------------
__global__ __launch_bounds__(256) void k4_final(const unsigned short* __restrict__ xbf,
                                                const float* __restrict__ s,
                                                const float* __restrict__ rnorm,
                                                const float* __restrict__ pm,
                                                const float* __restrict__ pz,
                                                const float* __restrict__ ps,
                                                float* __restrict__ out) {
  int tid = threadIdx.x;
  int wid = tid >> 6, lane = tid & 63;
  int row = blockIdx.x * 4 + wid;
  const bf16x8* xr = (const bf16x8*)(xbf + (size_t)row * 1024);
  const float4* s4 = (const float4*)s;
  float dot = 0.f;
#pragma unroll
  for (int j = 0; j < 2; ++j) {
    bf16x8 v = xr[lane + j * 64];
    float4 sa = s4[(lane + j * 64) * 2];
    float4 sb = s4[(lane + j * 64) * 2 + 1];
    dot += bf2f((unsigned short)v[0]) * sa.x + bf2f((unsigned short)v[1]) * sa.y +
           bf2f((unsigned short)v[2]) * sa.z + bf2f((unsigned short)v[3]) * sa.w +
           bf2f((unsigned short)v[4]) * sb.x + bf2f((unsigned short)v[5]) * sb.y +
           bf2f((unsigned short)v[6]) * sb.z + bf2f((unsigned short)v[7]) * sb.w;
  }
#pragma unroll
  for (int m = 1; m < 64; m <<= 1) dot += __shfl_xor(dot, m);
  if (lane == 0) {
    float mv[8], zv[8], svv[8];
    float M = -1e30f;
#pragma unroll
    for (int c = 0; c < 8; ++c) {
      mv[c] = pm[(size_t)c * 8192 + row];
      zv[c] = pz[(size_t)c * 8192 + row];
      svv[c] = ps[(size_t)c * 8192 + row];
      M = fmaxf(M, mv[c]);
    }
    float Z = 0.f, S = 0.f;
#pragma unroll
    for (int c = 0; c < 8; ++c) {
      float e = expf(mv[c] - M);
      Z += zv[c] * e;
      S += e * (svv[c] + (mv[c] - M) * zv[c]);
    }
    float loss = S / Z - logf(Z);
    out[row] = loss * dot * rnorm[row] * (1.f / 8192.f);
  }
}

// ---------------------------------------------------------------------------
extern "C" void kernel_launch(void* const* d_in, const int* in_sizes, int n_in,
                              void* d_out, int out_size, void* d_ws, size_t ws_size,
                              hipStream_t stream) {
  (void)in_sizes; (void)n_in; (void)out_size; (void)ws_size;
  const float* x = (const float*)d_in[0];
  const float* W = (const float*)d_in[1];
  const float* b = (const float*)d_in[2];
  float* out = (float*)d_out;
  char* ws = (char*)d_ws;

  unsigned short* Wt = (unsigned short*)(ws + 0);           // 2 MiB
  unsigned short* xbf = (unsigned short*)(ws + 2097152);    // 16 MiB
  float* rnorm = (float*)(ws + 18874368);                   // 32 KiB
  float* s = (float*)(ws + 18907136);                       // 4 KiB
  float* pm = (float*)(ws + 18915328);                      // 256 KiB
  float* pz = (float*)(ws + 18915328 + 262144);
  float* ps = (float*)(ws + 18915328 + 524288);

  hipMemsetAsync(s, 0, 4096, stream);
  k01_prep<<<256, 1024, 0, stream>>>(W, Wt, x, xbf, rnorm, s);
  k3_gemm<<<256, 512, 0, stream>>>(xbf, Wt, b, pm, pz, ps);
  k4_final<<<2048, 256, 0, stream>>>(xbf, s, rnorm, pm, pz, ps, out);
}